// Round 12
// baseline (1358.010 us; speedup 1.0000x reference)
//
#include <hip/hip_runtime.h>

typedef unsigned short u16;
typedef float f32x4 __attribute__((ext_vector_type(4)));
typedef __bf16 bf16v8 __attribute__((ext_vector_type(8)));
typedef u16 u16x4 __attribute__((ext_vector_type(4)));

#define WAITV(n) asm volatile("s_waitcnt vmcnt(" #n ")" ::: "memory")
#define BAR() asm volatile("s_barrier" ::: "memory")
#define LGKM0() do { asm volatile("s_waitcnt lgkmcnt(0)" ::: "memory"); \
                     __builtin_amdgcn_sched_barrier(0); } while (0)

__device__ __forceinline__ u16 f2bf(float f) {
  union { float f; unsigned int u; } v; v.f = f;
  unsigned int x = v.u;
  x += 0x7fffu + ((x >> 16) & 1u);   // round-to-nearest-even
  return (u16)(x >> 16);
}

__device__ __forceinline__ float bf2f(u16 b) {
  union { unsigned int u; float f; } v; v.u = ((unsigned int)b) << 16;
  return v.f;
}

__device__ __forceinline__ int refl(int i, int n) {
  i = (i < 0) ? -i : i;
  return (i >= n) ? (2 * n - 2 - i) : i;
}

__device__ __forceinline__ void gload_lds16(const void* g, void* l) {
  __builtin_amdgcn_global_load_lds(
      (const __attribute__((address_space(1))) void*)g,
      (__attribute__((address_space(3))) void*)l, 16, 0, 0);
}

enum { EPI_BF16_BIAS = 0, EPI_F32 = 1, EPI_BF16 = 2, EPI_F32_RES = 3, EPI_GELU = 4,
       EPI_BF16_BIASROW = 5 };

// XCD-aware bijective block remap (m204).
__device__ __forceinline__ void xcd_remap(int& bx, int& by, int& bz) {
  const int gx = gridDim.x, gy = gridDim.y;
  const int nwg = gx * gy * (int)gridDim.z;
  const int orig = ((int)blockIdx.z * gy + (int)blockIdx.y) * gx + (int)blockIdx.x;
  const int q = nwg >> 3, r = nwg & 7;
  const int xcd = orig & 7, loc = orig >> 3;
  const int swz = (xcd < r ? xcd * (q + 1) : r * (q + 1) + (xcd - r) * q) + loc;
  const int gxy = gx * gy;
  bz = swz / gxy;
  const int rem = swz - bz * gxy;
  by = rem / gx; bx = rem - by * gx;
}

// ---------------------------------------------------------------------------
// gemm256, 8-phase (round-5/7 verified): C[m,n]=sum_k A[m,k]*Bt[n,k].
// 256x256, BK=64, 512thr/8waves, 2 LDS bufs (128KiB), vmcnt(6) 1x/K-tile.
// Swizzle: 16B chunk c of 128B row r stored at chunk c^(r&7) (both sides).
// NOTE: 1 block/CU is register-forced (acc=128 VGPR); do NOT try 2 blocks/CU.
// Keep Q/K and V as SEPARATE dispatches (merged version thrashes L2 — r8/r9).
// ---------------------------------------------------------------------------
template <int EPI>
__global__ __launch_bounds__(512, 2) void gemm256(
    const u16* __restrict__ A, const u16* __restrict__ Bt, void* __restrict__ Cp,
    const float* __restrict__ bias, int K, int Nld, long sA, long sB, long sC, long sBias)
{
  extern __shared__ __align__(16) u16 smem[];  // buf d: A at d*32768, B at +16384

  const int t = threadIdx.x;
  int bx, by, bz; xcd_remap(bx, by, bz);
  const int m0 = by * 256, n0 = bx * 256;

  const long Kb = (long)K * 2;
  const int sr8 = t >> 3;                         // 0..63 (8 threads/row)
  const int schunk = ((t & 7) ^ (sr8 & 7)) * 16;  // swizzled source byte-col
  const char* Ag = (const char*)(A + (long)bz * sA + (long)m0 * K) + (long)sr8 * Kb + schunk;
  const char* Bg = (const char*)(Bt + (long)bz * sB + (long)n0 * K) + (long)sr8 * Kb + schunk;

  auto SA = [&](int d, int kt, int i0, int i1) {
    const long ko = (long)kt * 128;
    gload_lds16(Ag + (long)i0 * 64 * Kb + ko, &smem[d * 32768 + i0 * 4096 + t * 8]);
    gload_lds16(Ag + (long)i1 * 64 * Kb + ko, &smem[d * 32768 + i1 * 4096 + t * 8]);
  };
  auto SB = [&](int d, int kt, int i0, int i1) {
    const long ko = (long)kt * 128;
    gload_lds16(Bg + (long)i0 * 64 * Kb + ko, &smem[d * 32768 + 16384 + i0 * 4096 + t * 8]);
    gload_lds16(Bg + (long)i1 * 64 * Kb + ko, &smem[d * 32768 + 16384 + i1 * 4096 + t * 8]);
  };

  const int w = t >> 6, lane = t & 63;
  const int wm = (w >> 2) * 128, wn = (w & 3) * 64;   // 2M x 4N waves
  const int lr = lane & 15, hi = lane >> 4;
  const int rc0 = ((0 * 4 + hi) ^ (lr & 7)) * 8;
  const int rc1 = ((1 * 4 + hi) ^ (lr & 7)) * 8;

  f32x4 acc[8][4];
  const f32x4 vzero = {0.f, 0.f, 0.f, 0.f};
#pragma unroll
  for (int i = 0; i < 8; i++)
#pragma unroll
    for (int j = 0; j < 4; j++) acc[i][j] = vzero;

  const int NT = K >> 6, NI = NT >> 1;

  SA(0, 0, 0, 1); SA(0, 0, 2, 3); SB(0, 0, 0, 1); SB(0, 0, 2, 3);
  SB(1, 1, 0, 2); SB(1, 1, 1, 3); SA(1, 1, 0, 2);
  WAITV(6);
  BAR();

  for (int i = 0; i < NI; i++) {
    const int t0 = 2 * i;
    const bool last = (i == NI - 1);
#pragma unroll
    for (int h = 0; h < 2; h++) {
      const u16* Ad = &smem[h * 32768];
      const u16* Bd = Ad + 16384;
      bf16v8 b8[4][2];
#pragma unroll
      for (int q = 0; q < 4; q++) {
        bf16v8 a8[2][2];
#pragma unroll
        for (int j = 0; j < 2; j++) {
          const int rbase = (wm + (2 * q + j) * 16 + lr) * 64;
          a8[j][0] = *(const bf16v8*)&Ad[rbase + rc0];
          a8[j][1] = *(const bf16v8*)&Ad[rbase + rc1];
        }
        if (q == 0) {
#pragma unroll
          for (int ni = 0; ni < 4; ni++) {
            const int rbase = (wn + ni * 16 + lr) * 64;
            b8[ni][0] = *(const bf16v8*)&Bd[rbase + rc0];
            b8[ni][1] = *(const bf16v8*)&Bd[rbase + rc1];
          }
        }
        if (h == 0) {
          if (q == 0)           SA(1, t0 + 1, 1, 3);
          else if (!last) {
            if (q == 1)         SB(0, t0 + 2, 0, 2);
            else if (q == 2)    SB(0, t0 + 2, 1, 3);
            else                SA(0, t0 + 2, 0, 2);
          }
        } else if (!last) {
          if (q == 0)           SA(0, t0 + 2, 1, 3);
          else if (q == 1)      SB(1, t0 + 3, 0, 2);
          else if (q == 2)      SB(1, t0 + 3, 1, 3);
          else                  SA(1, t0 + 3, 0, 2);
        }
        BAR();
        LGKM0();
        __builtin_amdgcn_s_setprio(1);
#pragma unroll
        for (int j = 0; j < 2; j++)
#pragma unroll
          for (int ni = 0; ni < 4; ni++) {
            acc[2 * q + j][ni] = __builtin_amdgcn_mfma_f32_16x16x32_bf16(a8[j][0], b8[ni][0], acc[2 * q + j][ni], 0, 0, 0);
            acc[2 * q + j][ni] = __builtin_amdgcn_mfma_f32_16x16x32_bf16(a8[j][1], b8[ni][1], acc[2 * q + j][ni], 0, 0, 0);
          }
        __builtin_amdgcn_s_setprio(0);
        if (h == 0 && q == 3) { if (last) { WAITV(0); } else { WAITV(6); } }
        if (h == 1 && q == 3 && !last) { WAITV(6); }
        BAR();
      }
    }
  }

#pragma unroll
  for (int mi = 0; mi < 8; mi++) {
    const int r0 = m0 + wm + mi * 16 + hi * 4;
#pragma unroll
    for (int ni = 0; ni < 4; ni++) {
      const int col = n0 + wn + ni * 16 + lr;
      float bvv = 0.f;
      if constexpr (EPI == EPI_BF16_BIAS) bvv = bias[bz * sBias + col];
#pragma unroll
      for (int j = 0; j < 4; j++) {
        const long idx = (long)(r0 + j) * Nld + col;
        float val = acc[mi][ni][j] + bvv;
        if constexpr (EPI == EPI_BF16_BIASROW) val += bias[r0 + j];
        if constexpr (EPI == EPI_BF16_BIAS || EPI == EPI_BF16 || EPI == EPI_BF16_BIASROW) {
          ((u16*)Cp + (long)bz * sC)[idx] = f2bf(val);
        } else {
          ((float*)Cp + (long)bz * sC)[idx] = val;
        }
      }
    }
  }
}

// ---------------------------------------------------------------------------
// gemm128 v2 (round-7 proven): 128x128, BK=64, 512 thr / 8 waves (64x32
// wave-tiles, 2Mx4N), 2 bufs (64KiB), counted vmcnt(4), ks-outer MFMA order.
// ldb = B row stride in elements. A row stride = K.
// EPI_BF16_BIASROW added (row-indexed bias, for transposed V-proj).
// ---------------------------------------------------------------------------
template <int EPI>
__global__ __launch_bounds__(512, 4) void gemm128(
    const u16* __restrict__ A, const u16* __restrict__ Bt, void* __restrict__ Cp,
    const float* __restrict__ bias, int K, int ldb, int Nld, long sA, long sB, long sC)
{
  extern __shared__ __align__(16) u16 smem[];  // buf d: A at d*16384, B at +8192

  const int t = threadIdx.x;
  int bx, by, bz; xcd_remap(bx, by, bz);
  const int m0 = by * 128, n0 = bx * 128;

  const long Ka = (long)K * 2;
  const long Kb2 = (long)ldb * 2;
  const int sr8 = t >> 3;                         // 0..63
  const int schunk = ((t & 7) ^ (sr8 & 7)) * 16;  // swizzled source byte-col
  const char* Ag = (const char*)(A + (long)bz * sA + (long)m0 * K) + (long)sr8 * Ka + schunk;
  const char* Bg = (const char*)(Bt + (long)bz * sB + (long)n0 * ldb) + (long)sr8 * Kb2 + schunk;

  auto STAGE = [&](int d, int kt) {
    const long ko = (long)kt * 128;
    gload_lds16(Ag + ko,                &smem[d * 16384 + t * 8]);
    gload_lds16(Ag + 64 * Ka + ko,      &smem[d * 16384 + 4096 + t * 8]);
    gload_lds16(Bg + ko,                &smem[d * 16384 + 8192 + t * 8]);
    gload_lds16(Bg + 64 * Kb2 + ko,     &smem[d * 16384 + 12288 + t * 8]);
  };

  const int w = t >> 6, lane = t & 63;
  const int wm = (w >> 2) * 64, wn = (w & 3) * 32;   // 2M x 4N waves, 64x32 tile
  const int lr = lane & 15, hi = lane >> 4;
  const int rc0 = ((0 * 4 + hi) ^ (lr & 7)) * 8;
  const int rc1 = ((1 * 4 + hi) ^ (lr & 7)) * 8;

  f32x4 acc[4][2];
  const f32x4 vzero = {0.f, 0.f, 0.f, 0.f};
#pragma unroll
  for (int i = 0; i < 4; i++)
#pragma unroll
    for (int j = 0; j < 2; j++) acc[i][j] = vzero;

  const int NT = K >> 6;
  STAGE(0, 0);
  STAGE(1, 1);

  for (int kt = 0; kt < NT; kt++) {
    const int d = kt & 1;
    if (kt + 1 < NT) { WAITV(4); } else { WAITV(0); }
    BAR();

    const u16* Ad = &smem[d * 16384];
    const u16* Bd = Ad + 8192;
    bf16v8 a8[4][2], b8[2][2];
#pragma unroll
    for (int mi = 0; mi < 4; mi++) {
      const int rbase = (wm + mi * 16 + lr) * 64;
      a8[mi][0] = *(const bf16v8*)&Ad[rbase + rc0];
      a8[mi][1] = *(const bf16v8*)&Ad[rbase + rc1];
    }
#pragma unroll
    for (int ni = 0; ni < 2; ni++) {
      const int rbase = (wn + ni * 16 + lr) * 64;
      b8[ni][0] = *(const bf16v8*)&Bd[rbase + rc0];
      b8[ni][1] = *(const bf16v8*)&Bd[rbase + rc1];
    }
    __builtin_amdgcn_s_setprio(1);
#pragma unroll
    for (int ks = 0; ks < 2; ks++)
#pragma unroll
      for (int mi = 0; mi < 4; mi++)
#pragma unroll
        for (int ni = 0; ni < 2; ni++)
          acc[mi][ni] = __builtin_amdgcn_mfma_f32_16x16x32_bf16(a8[mi][ks], b8[ni][ks], acc[mi][ni], 0, 0, 0);
    __builtin_amdgcn_s_setprio(0);
    asm volatile("s_waitcnt lgkmcnt(0)\n\ts_barrier" ::: "memory");
    if (kt + 2 < NT) STAGE(d, kt + 2);
  }

#pragma unroll
  for (int mi = 0; mi < 4; mi++) {
    const int r0 = m0 + wm + mi * 16 + hi * 4;
#pragma unroll
    for (int ni = 0; ni < 2; ni++) {
      const int col = n0 + wn + ni * 16 + lr;
      float bvv = 0.f;
      if constexpr (EPI == EPI_F32_RES || EPI == EPI_GELU) bvv = bias[col];
#pragma unroll
      for (int j = 0; j < 4; j++) {
        const long idx = (long)(r0 + j) * Nld + col;
        float val = acc[mi][ni][j] + bvv;
        if constexpr (EPI == EPI_BF16_BIASROW) val += bias[r0 + j];
        if constexpr (EPI == EPI_F32) {
          ((float*)Cp + (long)bz * sC)[idx] = val;
        } else if constexpr (EPI == EPI_F32_RES) {
          ((float*)Cp + (long)bz * sC)[idx] += val;
        } else if constexpr (EPI == EPI_GELU) {
          const float gv = 0.5f * val * (1.f + erff(val * 0.70710678118654752440f));
          ((u16*)Cp + (long)bz * sC)[idx] = f2bf(gv);
        } else {
          ((u16*)Cp + (long)bz * sC)[idx] = f2bf(val);
        }
      }
    }
  }
}

// ---------------------------------------------------------------------------
// gemm_pv (round-11, neutral-vs-r7 but kept): tile 128x256, 8 waves of 64x64
// wave-tiles, BK=64, 2 LDS bufs (96KiB), counted vmcnt(6).
// ---------------------------------------------------------------------------
__global__ __launch_bounds__(512, 2) void gemm_pv(
    const u16* __restrict__ P, const u16* __restrict__ vT, u16* __restrict__ Cp)
{
  extern __shared__ __align__(16) u16 smem[];  // buf d at d*24576: A 8192, B at +8192

  const int t = threadIdx.x;
  int bx, by, bz; xcd_remap(bx, by, bz);       // grid (12, 9, 4)
  const int m0 = by * 128, n0 = bx * 256;

  const int sr8 = t >> 3;                         // 0..63
  const int schunk = ((t & 7) ^ (sr8 & 7)) * 16;  // swizzled source byte-col
  const char* Ag = (const char*)(P + (long)bz * 1327104 + (long)m0 * 1152)
                   + (long)sr8 * 2304 + schunk;
  const char* Bg = (const char*)(vT + (long)n0 * 4608 + (long)bz * 1152)
                   + (long)sr8 * 9216 + schunk;

  auto STAGE = [&](int d, int kt) {
    const long ko = (long)kt * 128;
#pragma unroll
    for (int i = 0; i < 2; i++)
      gload_lds16(Ag + (long)i * 64 * 2304 + ko, &smem[d * 24576 + i * 4096 + t * 8]);
#pragma unroll
    for (int i = 0; i < 4; i++)
      gload_lds16(Bg + (long)i * 64 * 9216 + ko, &smem[d * 24576 + 8192 + i * 4096 + t * 8]);
  };

  const int w = t >> 6, lane = t & 63;
  const int wm = (w >> 2) * 64, wn = (w & 3) * 64;   // 2M x 4N waves, 64x64 tile
  const int lr = lane & 15, hi = lane >> 4;
  const int rc0 = ((0 * 4 + hi) ^ (lr & 7)) * 8;
  const int rc1 = ((1 * 4 + hi) ^ (lr & 7)) * 8;

  f32x4 acc[4][4];
  const f32x4 vzero = {0.f, 0.f, 0.f, 0.f};
#pragma unroll
  for (int i = 0; i < 4; i++)
#pragma unroll
    for (int j = 0; j < 4; j++) acc[i][j] = vzero;

  const int NT = 18;   // K = 1152
  STAGE(0, 0);
  STAGE(1, 1);

  for (int kt = 0; kt < NT; kt++) {
    const int d = kt & 1;
    if (kt + 1 < NT) { WAITV(6); } else { WAITV(0); }
    BAR();

    const u16* Ad = &smem[d * 24576];
    const u16* Bd = Ad + 8192;
    bf16v8 a8[4][2], b8[4][2];
#pragma unroll
    for (int mi = 0; mi < 4; mi++) {
      const int rbase = (wm + mi * 16 + lr) * 64;
      a8[mi][0] = *(const bf16v8*)&Ad[rbase + rc0];
      a8[mi][1] = *(const bf16v8*)&Ad[rbase + rc1];
    }
#pragma unroll
    for (int ni = 0; ni < 4; ni++) {
      const int rbase = (wn + ni * 16 + lr) * 64;
      b8[ni][0] = *(const bf16v8*)&Bd[rbase + rc0];
      b8[ni][1] = *(const bf16v8*)&Bd[rbase + rc1];
    }
    __builtin_amdgcn_s_setprio(1);
#pragma unroll
    for (int ks = 0; ks < 2; ks++)
#pragma unroll
      for (int mi = 0; mi < 4; mi++)
#pragma unroll
        for (int ni = 0; ni < 4; ni++)
          acc[mi][ni] = __builtin_amdgcn_mfma_f32_16x16x32_bf16(a8[mi][ks], b8[ni][ks], acc[mi][ni], 0, 0, 0);
    __builtin_amdgcn_s_setprio(0);
    asm volatile("s_waitcnt lgkmcnt(0)\n\ts_barrier" ::: "memory");
    if (kt + 2 < NT) STAGE(d, kt + 2);
  }

#pragma unroll
  for (int mi = 0; mi < 4; mi++) {
    const int r0 = m0 + wm + mi * 16 + hi * 4;
#pragma unroll
    for (int ni = 0; ni < 4; ni++) {
      const int col = n0 + wn + ni * 16 + lr;
#pragma unroll
      for (int j = 0; j < 4; j++) {
        (Cp + (long)bz * 3538944)[(long)(r0 + j) * 3072 + col] = f2bf(acc[mi][ni][j]);
      }
    }
  }
}

// ---------------------------------------------------------------------------
// norm3: fused {z=0: LN(x f32)}, {z=1: patch+LN(dr_ref)}, {z=2: patch+LN(cl_ref)}
// -> bf16 slots of xkv_ln. grid (1152, 4, 3), block 256. (verified round 9)
// ---------------------------------------------------------------------------
__global__ __launch_bounds__(256) void norm3_kernel(const float* __restrict__ X,
    const float* __restrict__ dr_ref, const float* __restrict__ cl_ref,
    const float* __restrict__ g, const float* __restrict__ be,
    u16* __restrict__ Y3, int shift)
{
  const int n = blockIdx.x, b = blockIdx.y, z = blockIdx.z, t = threadIdx.x;
  const long row = (long)b * 1152 + n;
  u16* yr = Y3 + (size_t)z * 4718592 + row * 1024;
  const int d0 = t * 4;
  float v[4];
  if (z == 0) {
    const f32x4 vv = *(const f32x4*)&X[row * 1024 + d0];
    v[0] = vv[0]; v[1] = vv[1]; v[2] = vv[2]; v[3] = vv[3];
  } else {
    if (n >= 1089) {
      const u16x4 zz = {0, 0, 0, 0};
      *(u16x4*)&yr[d0] = zz;
      return;
    }
    const float* img = (z == 1) ? dr_ref : cl_ref;
    const int p = shift * 2;
    const int ph = n / 33, pw = n - ph * 33;
    const int c = d0 >> 6, kh = (d0 >> 3) & 7, kw0 = d0 & 7;
    const int hh = refl(ph * 8 + kh - p, 256);
    const float* src = img + ((long)(b * 16 + c) * 256 + hh) * 256;
#pragma unroll
    for (int i = 0; i < 4; i++) v[i] = src[refl(pw * 8 + kw0 + i - p, 256)];
  }
  float s = v[0] + v[1] + v[2] + v[3];
  float q = v[0]*v[0] + v[1]*v[1] + v[2]*v[2] + v[3]*v[3];
#pragma unroll
  for (int off = 32; off; off >>= 1) { s += __shfl_xor(s, off); q += __shfl_xor(q, off); }
  __shared__ float red[8];
  if ((t & 63) == 0) { red[t >> 6] = s; red[4 + (t >> 6)] = q; }
  __syncthreads();
  s = red[0] + red[1] + red[2] + red[3];
  q = red[4] + red[5] + red[6] + red[7];
  const float mean = s * (1.f / 1024.f);
  const float rstd = rsqrtf(q * (1.f / 1024.f) - mean * mean + 1e-5f);
  u16x4 o;
#pragma unroll
  for (int i = 0; i < 4; i++) o[i] = f2bf((v[i] - mean) * rstd * g[d0 + i] + be[d0 + i]);
  *(u16x4*)&yr[d0] = o;
}

// ---------------------------------------------------------------------------
// LayerNorm: f32 [row,1024] -> bf16 (FF pre-norm)
// ---------------------------------------------------------------------------
__global__ __launch_bounds__(256) void ln_kernel(const float* __restrict__ X,
    const float* __restrict__ g, const float* __restrict__ be, u16* __restrict__ Y)
{
  const long row = blockIdx.x;
  const int t = threadIdx.x;
  const float* xr = X + row * 1024;
  f32x4 v = *(const f32x4*)&xr[t * 4];
  float s = v[0] + v[1] + v[2] + v[3];
  float q = v[0]*v[0] + v[1]*v[1] + v[2]*v[2] + v[3]*v[3];
#pragma unroll
  for (int off = 32; off; off >>= 1) { s += __shfl_xor(s, off); q += __shfl_xor(q, off); }
  __shared__ float red[8];
  if ((t & 63) == 0) { red[t >> 6] = s; red[4 + (t >> 6)] = q; }
  __syncthreads();
  s = red[0] + red[1] + red[2] + red[3];
  q = red[4] + red[5] + red[6] + red[7];
  const float mean = s * (1.f / 1024.f);
  const float rstd = rsqrtf(q * (1.f / 1024.f) - mean * mean + 1e-5f);
  f32x4 gv = *(const f32x4*)&g[t * 4];
  f32x4 bv = *(const f32x4*)&be[t * 4];
  u16x4 o;
#pragma unroll
  for (int i = 0; i < 4; i++) o[i] = f2bf((v[i] - mean) * rstd * gv[i] + bv[i]);
  *(u16x4*)&Y[row * 1024 + t * 4] = o;
}

// ---------------------------------------------------------------------------
// Patch (reflect-pad + unfold) -> f32 x buffer; pad rows zeroed. rows=1152/b
// ---------------------------------------------------------------------------
__global__ __launch_bounds__(256) void patch_kernel(const float* __restrict__ img,
    float* __restrict__ X, int shift)
{
  const int n = blockIdx.x, b = blockIdx.y, t = threadIdx.x;
  float* xr = X + ((long)b * 1152 + n) * 1024;
  if (n >= 1089) {
    const f32x4 z = {0.f, 0.f, 0.f, 0.f};
    *(f32x4*)&xr[t * 4] = z;
    return;
  }
  const int p = shift * 2;
  const int ph = n / 33, pw = n - ph * 33;
  const int d0 = t * 4;
  const int c = d0 >> 6, kh = (d0 >> 3) & 7, kw0 = d0 & 7;
  const int hh = refl(ph * 8 + kh - p, 256);
  const float* src = img + ((long)(b * 16 + c) * 256 + hh) * 256;
  f32x4 v;
#pragma unroll
  for (int i = 0; i < 4; i++) v[i] = src[refl(pw * 8 + kw0 + i - p, 256)];
  *(f32x4*)&xr[d0] = v;
}

// ---------------------------------------------------------------------------
// Row softmax from bf16 logits, masked (cols < 1089), scale 1/32, bf16 out.
// ---------------------------------------------------------------------------
__global__ __launch_bounds__(256) void softmax_kernel(const u16* __restrict__ L,
    u16* __restrict__ P)
{
  const int r = blockIdx.x, b = blockIdx.y, t = threadIdx.x;
  const u16* Lr = L + ((long)b * 1152 + r) * 1152;
  u16* Pr = P + ((long)b * 1152 + r) * 1152;
  float v[5];
  float mx = -1e30f;
#pragma unroll
  for (int i = 0; i < 5; i++) {
    const int j = t + i * 256;
    v[i] = (j < 1089) ? bf2f(Lr[j]) * 0.03125f : -1e30f;
    mx = fmaxf(mx, v[i]);
  }
#pragma unroll
  for (int off = 32; off; off >>= 1) mx = fmaxf(mx, __shfl_xor(mx, off));
  __shared__ float sm[4];
  if ((t & 63) == 0) sm[t >> 6] = mx;
  __syncthreads();
  mx = fmaxf(fmaxf(sm[0], sm[1]), fmaxf(sm[2], sm[3]));
  float p[5];
  float s = 0.f;
#pragma unroll
  for (int i = 0; i < 5; i++) {
    const int j = t + i * 256;
    p[i] = (j < 1089) ? __expf(v[i] - mx) : 0.f;
    s += p[i];
  }
#pragma unroll
  for (int off = 32; off; off >>= 1) s += __shfl_xor(s, off);
  __shared__ float ss[4];
  if ((t & 63) == 0) ss[t >> 6] = s;
  __syncthreads();
  const float inv = 1.f / (ss[0] + ss[1] + ss[2] + ss[3]);
#pragma unroll
  for (int i = 0; i < 5; i++) {
    const int j = t + i * 256;
    if (j < 1152) Pr[j] = f2bf(p[i] * inv);
  }
}

// ---------------------------------------------------------------------------
// Weight transpose (f32 -> bf16, W[K][N] -> Wt[N][K])
// ---------------------------------------------------------------------------
__global__ __launch_bounds__(256) void wtrans_kernel(const float* __restrict__ W,
    u16* __restrict__ Wt, int K, int N)
{
  __shared__ float tile[32][33];
  const int n0 = blockIdx.x * 32, k0 = blockIdx.y * 32;
  const int tx = threadIdx.x & 31, ty = threadIdx.x >> 5;
#pragma unroll
  for (int i = 0; i < 4; i++)
    tile[ty + 8 * i][tx] = W[(long)(k0 + ty + 8 * i) * N + n0 + tx];
  __syncthreads();
#pragma unroll
  for (int i = 0; i < 4; i++)
    Wt[(long)(n0 + ty + 8 * i) * K + k0 + tx] = f2bf(tile[tx][ty + 8 * i]);
}

__global__ __launch_bounds__(256) void catbias_kernel(const float* __restrict__ a,
    const float* __restrict__ b, const float* __restrict__ c, float* __restrict__ o)
{
  const int i = blockIdx.x * 256 + threadIdx.x;  // 3072
  o[i] = a[i]; o[3072 + i] = b[i]; o[6144 + i] = c[i];
}

// ---------------------------------------------------------------------------
// Unpatch (inverse unfold + crop) -> f32 output
// ---------------------------------------------------------------------------
__global__ __launch_bounds__(256) void unpatch_kernel(const float* __restrict__ X,
    float* __restrict__ out)
{
  const int idx = blockIdx.x * 256 + threadIdx.x;  // one per 4 floats
  const int w = (idx & 63) * 4;
  const int h = (idx >> 6) & 255;
  const int c = (idx >> 14) & 15;
  const int b = idx >> 18;
  const int ph = h >> 3, kh = h & 7, pw = w >> 3, kw = w & 7;
  const long row = (long)b * 1152 + ph * 33 + pw;
  const int d = c * 64 + kh * 8 + kw;
  const f32x4 v = *(const f32x4*)&X[row * 1024 + d];
  *(f32x4*)&out[((long)(b * 16 + c) * 256 + h) * 256 + w] = v;
}

// ---------------------------------------------------------------------------
extern "C" void kernel_launch(void* const* d_in, const int* in_sizes, int n_in,
                              void* d_out, int out_size, void* d_ws, size_t ws_size,
                              hipStream_t stream)
{
  (void)in_sizes; (void)n_in; (void)out_size; (void)ws_size;
  const float* dr_img = (const float*)d_in[0];
  const float* dr_ref = (const float*)d_in[1];
  const float* cl_ref = (const float*)d_in[2];
  const float* ln_g = (const float*)d_in[3];
  const float* ln_be = (const float*)d_in[4];
  const float* Wq = (const float*)d_in[5];
  const float* bq = (const float*)d_in[6];
  const float* Wk = (const float*)d_in[7];
  const float* bk = (const float*)d_in[8];
  const float* Wv = (const float*)d_in[9];
  const float* bv = (const float*)d_in[10];
  const float* Wo = (const float*)d_in[11];
  const float* bo = (const float*)d_in[12];
  const float* ffg = (const float*)d_in[13];
  const float* ffb = (const float*)d_in[14];
  const float* W1 = (const float*)d_in[15];
  const float* b1 = (const float*)d_in[16];
  const float* W2 = (const float*)d_in[17];
  const float* b2 = (const float*)d_in[18];

  const long R = 1152;                 // padded tokens per batch (9*128)
  const long MR = 4 * R;               // 4608 = 18*256

  char* ws = (char*)d_ws;
  size_t off = 0;
  auto alloc = [&](size_t bytes) -> void* {
    void* pp = ws + off;
    off += (bytes + 255) & ~(size_t)255;
    return pp;
  };
  float* x    = (float*)alloc((size_t)MR * 1024 * 4);
  u16* xkv_ln = (u16*)alloc((size_t)3 * MR * 1024 * 2);  // x_ln / k_ln(=FF h) / v_ln
  u16* qkv    = (u16*)alloc((size_t)3 * MR * 3072 * 2);  // q(=attn_out) / k / V^T[3072][4608]
  u16* lgt    = (u16*)alloc((size_t)4 * R * R * 2);      // bf16 logits
  u16* P      = (u16*)alloc((size_t)4 * R * R * 2);
  u16* Wqkv_t = (u16*)alloc((size_t)3 * 3072 * 1024 * 2);
  u16* Wo_t   = (u16*)alloc((size_t)1024 * 3072 * 2);
  u16* W1_t   = (u16*)alloc((size_t)1024 * 1024 * 2);
  u16* W2_t   = (u16*)alloc((size_t)1024 * 1024 * 2);
  float* bcat = (float*)alloc((size_t)3 * 3072 * 4);

  u16* x_ln = xkv_ln;
  u16* v_ln = xkv_ln + (size_t)2 * MR * 1024;
  u16* h    = xkv_ln + (size_t)MR * 1024;      // FF hidden aliases k_ln slot
  u16* qp   = qkv;
  u16* kp   = qkv + (size_t)MR * 3072;
  u16* vT   = qkv + (size_t)2 * MR * 3072;     // [3072][4608]
  u16* Wv_t = Wqkv_t + (size_t)2 * 3072 * 1024;

  wtrans_kernel<<<dim3(96, 32), 256, 0, stream>>>(Wq, Wqkv_t, 1024, 3072);
  wtrans_kernel<<<dim3(96, 32), 256, 0, stream>>>(Wk, Wqkv_t + (size_t)3072 * 1024, 1024, 3072);
  wtrans_kernel<<<dim3(96, 32), 256, 0, stream>>>(Wv, Wv_t, 1024, 3072);
  wtrans_kernel<<<dim3(32, 96), 256, 0, stream>>>(Wo, Wo_t, 3072, 1024);
  wtrans_kernel<<<dim3(32, 32), 256, 0, stream>>>(W1, W1_t, 1024, 1024);
  wtrans_kernel<<<dim3(32, 32), 256, 0, stream>>>(W2, W2_t, 1024, 1024);
  catbias_kernel<<<12, 256, 0, stream>>>(bq, bk, bv, bcat);

  patch_kernel<<<dim3(1152, 4), 256, 0, stream>>>(dr_img, x, 0);

  const long sAp = (long)MR * 1024;        // proj A slot stride
  const long sBp = (long)3072 * 1024;      // proj W slot stride
  const long sCp = (long)MR * 3072;        // proj C slot stride
  const long sQb = R * 3072;               // per-batch stride in qp/kp
  const long sLb = R * R;

  for (int shift = 0; shift < 4; shift++) {
    // fused: LN(x) -> slot0 | patch+LN(dr_ref) -> slot1 | patch+LN(cl_ref) -> slot2
    norm3_kernel<<<dim3(1152, 4, 3), 256, 0, stream>>>(
        x, dr_ref, cl_ref, ln_g, ln_be, xkv_ln, shift);

    // Q/K projections, z-batched: [4608,1024] x [3072,1024]^T -> [4608,3072]
    gemm256<EPI_BF16_BIAS><<<dim3(12, 18, 2), 512, 131072, stream>>>(
        xkv_ln, Wqkv_t, qkv, bcat, 1024, 3072, sAp, sBp, sCp, 3072);

    // V^T projection via gemm128 (864 blocks, 2 blocks/CU):
    // [3072,1024] x [4608,1024]^T -> V^T[3072][4608], row bias bv
    gemm128<EPI_BF16_BIASROW><<<dim3(36, 24, 1), 512, 65536, stream>>>(
        Wv_t, v_ln, vT, bv, 1024, 1024, 4608, 0, 0, 0);

    // logits: per batch [1152,3072] x [1152,3072]^T -> [1152,1152] bf16
    gemm128<EPI_BF16><<<dim3(9, 9, 4), 512, 65536, stream>>>(
        qp, kp, lgt, nullptr, 3072, 3072, 1152, sQb, sQb, sLb);

    softmax_kernel<<<dim3(1152, 4), 256, 0, stream>>>(lgt, P);

    // PV: per batch [1152,1152] x V^T -> [1152,3072] (128x256 tile, 64x64 waves)
    gemm_pv<<<dim3(12, 9, 4), 512, 98304, stream>>>(P, vT, qp);

    // out-proj + residual: [4608,3072] x [1024,3072]^T -> += x
    gemm128<EPI_F32_RES><<<dim3(8, 36, 1), 512, 65536, stream>>>(
        qp, Wo_t, x, bo, 3072, 3072, 1024, 0, 0, 0);

    ln_kernel<<<(int)MR, 256, 0, stream>>>(x, ffg, ffb, x_ln);
    gemm128<EPI_GELU><<<dim3(8, 36, 1), 512, 65536, stream>>>(
        x_ln, W1_t, h, b1, 1024, 1024, 1024, 0, 0, 0);
    gemm128<EPI_F32_RES><<<dim3(8, 36, 1), 512, 65536, stream>>>(
        h, W2_t, x, b2, 1024, 1024, 1024, 0, 0, 0);
  }

  unpatch_kernel<<<4096, 256, 0, stream>>>(x, (float*)d_out);
}

// Round 13
// 1309.270 us; speedup vs baseline: 1.0372x; 1.0372x over previous
//
#include <hip/hip_runtime.h>

typedef unsigned short u16;
typedef float f32x4 __attribute__((ext_vector_type(4)));
typedef __bf16 bf16v8 __attribute__((ext_vector_type(8)));
typedef u16 u16x4 __attribute__((ext_vector_type(4)));

#define WAITV(n) asm volatile("s_waitcnt vmcnt(" #n ")" ::: "memory")
#define BAR() asm volatile("s_barrier" ::: "memory")
#define LGKM0() do { asm volatile("s_waitcnt lgkmcnt(0)" ::: "memory"); \
                     __builtin_amdgcn_sched_barrier(0); } while (0)

__device__ __forceinline__ u16 f2bf(float f) {
  union { float f; unsigned int u; } v; v.f = f;
  unsigned int x = v.u;
  x += 0x7fffu + ((x >> 16) & 1u);   // round-to-nearest-even
  return (u16)(x >> 16);
}

__device__ __forceinline__ float bf2f(u16 b) {
  union { unsigned int u; float f; } v; v.u = ((unsigned int)b) << 16;
  return v.f;
}

__device__ __forceinline__ int refl(int i, int n) {
  i = (i < 0) ? -i : i;
  return (i >= n) ? (2 * n - 2 - i) : i;
}

__device__ __forceinline__ void gload_lds16(const void* g, void* l) {
  __builtin_amdgcn_global_load_lds(
      (const __attribute__((address_space(1))) void*)g,
      (__attribute__((address_space(3))) void*)l, 16, 0, 0);
}

enum { EPI_BF16_BIAS = 0, EPI_F32 = 1, EPI_BF16 = 2, EPI_F32_RES = 3, EPI_GELU = 4,
       EPI_BF16_BIASROW = 5 };

// XCD-aware bijective block remap (m204).
__device__ __forceinline__ void xcd_remap(int& bx, int& by, int& bz) {
  const int gx = gridDim.x, gy = gridDim.y;
  const int nwg = gx * gy * (int)gridDim.z;
  const int orig = ((int)blockIdx.z * gy + (int)blockIdx.y) * gx + (int)blockIdx.x;
  const int q = nwg >> 3, r = nwg & 7;
  const int xcd = orig & 7, loc = orig >> 3;
  const int swz = (xcd < r ? xcd * (q + 1) : r * (q + 1) + (xcd - r) * q) + loc;
  const int gxy = gx * gy;
  bz = swz / gxy;
  const int rem = swz - bz * gxy;
  by = rem / gx; bx = rem - by * gx;
}

// ---------------------------------------------------------------------------
// gemm256, 8-phase (round-5/7 verified): C[m,n]=sum_k A[m,k]*Bt[n,k].
// 256x256, BK=64, 512thr/8waves, 2 LDS bufs (128KiB), vmcnt(6) 1x/K-tile.
// Swizzle: 16B chunk c of 128B row r stored at chunk c^(r&7) (both sides).
// NOTE: 1 block/CU is register-forced (acc=128 VGPR); do NOT try 2 blocks/CU.
// Keep Q/K and V as SEPARATE dispatches (merged version thrashes L2 — r8/r9).
// V-proj must stay 256^2 (128^2 retile = 2x staging traffic, regressed — r12).
// ---------------------------------------------------------------------------
template <int EPI>
__global__ __launch_bounds__(512, 2) void gemm256(
    const u16* __restrict__ A, const u16* __restrict__ Bt, void* __restrict__ Cp,
    const float* __restrict__ bias, int K, int Nld, long sA, long sB, long sC, long sBias)
{
  extern __shared__ __align__(16) u16 smem[];  // buf d: A at d*32768, B at +16384

  const int t = threadIdx.x;
  int bx, by, bz; xcd_remap(bx, by, bz);
  const int m0 = by * 256, n0 = bx * 256;

  const long Kb = (long)K * 2;
  const int sr8 = t >> 3;                         // 0..63 (8 threads/row)
  const int schunk = ((t & 7) ^ (sr8 & 7)) * 16;  // swizzled source byte-col
  const char* Ag = (const char*)(A + (long)bz * sA + (long)m0 * K) + (long)sr8 * Kb + schunk;
  const char* Bg = (const char*)(Bt + (long)bz * sB + (long)n0 * K) + (long)sr8 * Kb + schunk;

  auto SA = [&](int d, int kt, int i0, int i1) {
    const long ko = (long)kt * 128;
    gload_lds16(Ag + (long)i0 * 64 * Kb + ko, &smem[d * 32768 + i0 * 4096 + t * 8]);
    gload_lds16(Ag + (long)i1 * 64 * Kb + ko, &smem[d * 32768 + i1 * 4096 + t * 8]);
  };
  auto SB = [&](int d, int kt, int i0, int i1) {
    const long ko = (long)kt * 128;
    gload_lds16(Bg + (long)i0 * 64 * Kb + ko, &smem[d * 32768 + 16384 + i0 * 4096 + t * 8]);
    gload_lds16(Bg + (long)i1 * 64 * Kb + ko, &smem[d * 32768 + 16384 + i1 * 4096 + t * 8]);
  };

  const int w = t >> 6, lane = t & 63;
  const int wm = (w >> 2) * 128, wn = (w & 3) * 64;   // 2M x 4N waves
  const int lr = lane & 15, hi = lane >> 4;
  const int rc0 = ((0 * 4 + hi) ^ (lr & 7)) * 8;
  const int rc1 = ((1 * 4 + hi) ^ (lr & 7)) * 8;

  f32x4 acc[8][4];
  const f32x4 vzero = {0.f, 0.f, 0.f, 0.f};
#pragma unroll
  for (int i = 0; i < 8; i++)
#pragma unroll
    for (int j = 0; j < 4; j++) acc[i][j] = vzero;

  const int NT = K >> 6, NI = NT >> 1;

  SA(0, 0, 0, 1); SA(0, 0, 2, 3); SB(0, 0, 0, 1); SB(0, 0, 2, 3);
  SB(1, 1, 0, 2); SB(1, 1, 1, 3); SA(1, 1, 0, 2);
  WAITV(6);
  BAR();

  for (int i = 0; i < NI; i++) {
    const int t0 = 2 * i;
    const bool last = (i == NI - 1);
#pragma unroll
    for (int h = 0; h < 2; h++) {
      const u16* Ad = &smem[h * 32768];
      const u16* Bd = Ad + 16384;
      bf16v8 b8[4][2];
#pragma unroll
      for (int q = 0; q < 4; q++) {
        bf16v8 a8[2][2];
#pragma unroll
        for (int j = 0; j < 2; j++) {
          const int rbase = (wm + (2 * q + j) * 16 + lr) * 64;
          a8[j][0] = *(const bf16v8*)&Ad[rbase + rc0];
          a8[j][1] = *(const bf16v8*)&Ad[rbase + rc1];
        }
        if (q == 0) {
#pragma unroll
          for (int ni = 0; ni < 4; ni++) {
            const int rbase = (wn + ni * 16 + lr) * 64;
            b8[ni][0] = *(const bf16v8*)&Bd[rbase + rc0];
            b8[ni][1] = *(const bf16v8*)&Bd[rbase + rc1];
          }
        }
        if (h == 0) {
          if (q == 0)           SA(1, t0 + 1, 1, 3);
          else if (!last) {
            if (q == 1)         SB(0, t0 + 2, 0, 2);
            else if (q == 2)    SB(0, t0 + 2, 1, 3);
            else                SA(0, t0 + 2, 0, 2);
          }
        } else if (!last) {
          if (q == 0)           SA(0, t0 + 2, 1, 3);
          else if (q == 1)      SB(1, t0 + 3, 0, 2);
          else if (q == 2)      SB(1, t0 + 3, 1, 3);
          else                  SA(1, t0 + 3, 0, 2);
        }
        BAR();
        LGKM0();
        __builtin_amdgcn_s_setprio(1);
#pragma unroll
        for (int j = 0; j < 2; j++)
#pragma unroll
          for (int ni = 0; ni < 4; ni++) {
            acc[2 * q + j][ni] = __builtin_amdgcn_mfma_f32_16x16x32_bf16(a8[j][0], b8[ni][0], acc[2 * q + j][ni], 0, 0, 0);
            acc[2 * q + j][ni] = __builtin_amdgcn_mfma_f32_16x16x32_bf16(a8[j][1], b8[ni][1], acc[2 * q + j][ni], 0, 0, 0);
          }
        __builtin_amdgcn_s_setprio(0);
        if (h == 0 && q == 3) { if (last) { WAITV(0); } else { WAITV(6); } }
        if (h == 1 && q == 3 && !last) { WAITV(6); }
        BAR();
      }
    }
  }

#pragma unroll
  for (int mi = 0; mi < 8; mi++) {
    const int r0 = m0 + wm + mi * 16 + hi * 4;
#pragma unroll
    for (int ni = 0; ni < 4; ni++) {
      const int col = n0 + wn + ni * 16 + lr;
      float bvv = 0.f;
      if constexpr (EPI == EPI_BF16_BIAS) bvv = bias[bz * sBias + col];
#pragma unroll
      for (int j = 0; j < 4; j++) {
        const long idx = (long)(r0 + j) * Nld + col;
        float val = acc[mi][ni][j] + bvv;
        if constexpr (EPI == EPI_BF16_BIASROW) val += bias[r0 + j];
        if constexpr (EPI == EPI_BF16_BIAS || EPI == EPI_BF16 || EPI == EPI_BF16_BIASROW) {
          ((u16*)Cp + (long)bz * sC)[idx] = f2bf(val);
        } else {
          ((float*)Cp + (long)bz * sC)[idx] = val;
        }
      }
    }
  }
}

// ---------------------------------------------------------------------------
// gemm128 v2 (round-7 proven): 128x128, BK=64, 512 thr / 8 waves (64x32
// wave-tiles, 2Mx4N), 2 bufs (64KiB), counted vmcnt(4), ks-outer MFMA order.
// ldb = B row stride in elements.
// ---------------------------------------------------------------------------
template <int EPI>
__global__ __launch_bounds__(512, 4) void gemm128(
    const u16* __restrict__ A, const u16* __restrict__ Bt, void* __restrict__ Cp,
    const float* __restrict__ bias, int K, int ldb, int Nld, long sA, long sB, long sC)
{
  extern __shared__ __align__(16) u16 smem[];  // buf d: A at d*16384, B at +8192

  const int t = threadIdx.x;
  int bx, by, bz; xcd_remap(bx, by, bz);
  const int m0 = by * 128, n0 = bx * 128;

  const long Ka = (long)K * 2;
  const long Kb2 = (long)ldb * 2;
  const int sr8 = t >> 3;                         // 0..63
  const int schunk = ((t & 7) ^ (sr8 & 7)) * 16;  // swizzled source byte-col
  const char* Ag = (const char*)(A + (long)bz * sA + (long)m0 * K) + (long)sr8 * Ka + schunk;
  const char* Bg = (const char*)(Bt + (long)bz * sB + (long)n0 * ldb) + (long)sr8 * Kb2 + schunk;

  auto STAGE = [&](int d, int kt) {
    const long ko = (long)kt * 128;
    gload_lds16(Ag + ko,                &smem[d * 16384 + t * 8]);
    gload_lds16(Ag + 64 * Ka + ko,      &smem[d * 16384 + 4096 + t * 8]);
    gload_lds16(Bg + ko,                &smem[d * 16384 + 8192 + t * 8]);
    gload_lds16(Bg + 64 * Kb2 + ko,     &smem[d * 16384 + 12288 + t * 8]);
  };

  const int w = t >> 6, lane = t & 63;
  const int wm = (w >> 2) * 64, wn = (w & 3) * 32;   // 2M x 4N waves, 64x32 tile
  const int lr = lane & 15, hi = lane >> 4;
  const int rc0 = ((0 * 4 + hi) ^ (lr & 7)) * 8;
  const int rc1 = ((1 * 4 + hi) ^ (lr & 7)) * 8;

  f32x4 acc[4][2];
  const f32x4 vzero = {0.f, 0.f, 0.f, 0.f};
#pragma unroll
  for (int i = 0; i < 4; i++)
#pragma unroll
    for (int j = 0; j < 2; j++) acc[i][j] = vzero;

  const int NT = K >> 6;
  STAGE(0, 0);
  STAGE(1, 1);

  for (int kt = 0; kt < NT; kt++) {
    const int d = kt & 1;
    if (kt + 1 < NT) { WAITV(4); } else { WAITV(0); }
    BAR();

    const u16* Ad = &smem[d * 16384];
    const u16* Bd = Ad + 8192;
    bf16v8 a8[4][2], b8[2][2];
#pragma unroll
    for (int mi = 0; mi < 4; mi++) {
      const int rbase = (wm + mi * 16 + lr) * 64;
      a8[mi][0] = *(const bf16v8*)&Ad[rbase + rc0];
      a8[mi][1] = *(const bf16v8*)&Ad[rbase + rc1];
    }
#pragma unroll
    for (int ni = 0; ni < 2; ni++) {
      const int rbase = (wn + ni * 16 + lr) * 64;
      b8[ni][0] = *(const bf16v8*)&Bd[rbase + rc0];
      b8[ni][1] = *(const bf16v8*)&Bd[rbase + rc1];
    }
    __builtin_amdgcn_s_setprio(1);
#pragma unroll
    for (int ks = 0; ks < 2; ks++)
#pragma unroll
      for (int mi = 0; mi < 4; mi++)
#pragma unroll
        for (int ni = 0; ni < 2; ni++)
          acc[mi][ni] = __builtin_amdgcn_mfma_f32_16x16x32_bf16(a8[mi][ks], b8[ni][ks], acc[mi][ni], 0, 0, 0);
    __builtin_amdgcn_s_setprio(0);
    asm volatile("s_waitcnt lgkmcnt(0)\n\ts_barrier" ::: "memory");
    if (kt + 2 < NT) STAGE(d, kt + 2);
  }

#pragma unroll
  for (int mi = 0; mi < 4; mi++) {
    const int r0 = m0 + wm + mi * 16 + hi * 4;
#pragma unroll
    for (int ni = 0; ni < 2; ni++) {
      const int col = n0 + wn + ni * 16 + lr;
      float bvv = 0.f;
      if constexpr (EPI == EPI_F32_RES || EPI == EPI_GELU) bvv = bias[col];
#pragma unroll
      for (int j = 0; j < 4; j++) {
        const long idx = (long)(r0 + j) * Nld + col;
        const float val = acc[mi][ni][j] + bvv;
        if constexpr (EPI == EPI_F32) {
          ((float*)Cp + (long)bz * sC)[idx] = val;
        } else if constexpr (EPI == EPI_F32_RES) {
          ((float*)Cp + (long)bz * sC)[idx] += val;
        } else if constexpr (EPI == EPI_GELU) {
          const float gv = 0.5f * val * (1.f + erff(val * 0.70710678118654752440f));
          ((u16*)Cp + (long)bz * sC)[idx] = f2bf(gv);
        } else {
          ((u16*)Cp + (long)bz * sC)[idx] = f2bf(val);
        }
      }
    }
  }
}

// ---------------------------------------------------------------------------
// gemm_pv: tile 128x256, 8 waves of 64x64 wave-tiles, BK=64, 2 LDS bufs
// (96KiB), counted vmcnt(6).
// ---------------------------------------------------------------------------
__global__ __launch_bounds__(512, 2) void gemm_pv(
    const u16* __restrict__ P, const u16* __restrict__ vT, u16* __restrict__ Cp)
{
  extern __shared__ __align__(16) u16 smem[];  // buf d at d*24576: A 8192, B at +8192

  const int t = threadIdx.x;
  int bx, by, bz; xcd_remap(bx, by, bz);       // grid (12, 9, 4)
  const int m0 = by * 128, n0 = bx * 256;

  const int sr8 = t >> 3;                         // 0..63
  const int schunk = ((t & 7) ^ (sr8 & 7)) * 16;  // swizzled source byte-col
  const char* Ag = (const char*)(P + (long)bz * 1327104 + (long)m0 * 1152)
                   + (long)sr8 * 2304 + schunk;
  const char* Bg = (const char*)(vT + (long)n0 * 4608 + (long)bz * 1152)
                   + (long)sr8 * 9216 + schunk;

  auto STAGE = [&](int d, int kt) {
    const long ko = (long)kt * 128;
#pragma unroll
    for (int i = 0; i < 2; i++)
      gload_lds16(Ag + (long)i * 64 * 2304 + ko, &smem[d * 24576 + i * 4096 + t * 8]);
#pragma unroll
    for (int i = 0; i < 4; i++)
      gload_lds16(Bg + (long)i * 64 * 9216 + ko, &smem[d * 24576 + 8192 + i * 4096 + t * 8]);
  };

  const int w = t >> 6, lane = t & 63;
  const int wm = (w >> 2) * 64, wn = (w & 3) * 64;   // 2M x 4N waves, 64x64 tile
  const int lr = lane & 15, hi = lane >> 4;
  const int rc0 = ((0 * 4 + hi) ^ (lr & 7)) * 8;
  const int rc1 = ((1 * 4 + hi) ^ (lr & 7)) * 8;

  f32x4 acc[4][4];
  const f32x4 vzero = {0.f, 0.f, 0.f, 0.f};
#pragma unroll
  for (int i = 0; i < 4; i++)
#pragma unroll
    for (int j = 0; j < 4; j++) acc[i][j] = vzero;

  const int NT = 18;   // K = 1152
  STAGE(0, 0);
  STAGE(1, 1);

  for (int kt = 0; kt < NT; kt++) {
    const int d = kt & 1;
    if (kt + 1 < NT) { WAITV(6); } else { WAITV(0); }
    BAR();

    const u16* Ad = &smem[d * 24576];
    const u16* Bd = Ad + 8192;
    bf16v8 a8[4][2], b8[4][2];
#pragma unroll
    for (int mi = 0; mi < 4; mi++) {
      const int rbase = (wm + mi * 16 + lr) * 64;
      a8[mi][0] = *(const bf16v8*)&Ad[rbase + rc0];
      a8[mi][1] = *(const bf16v8*)&Ad[rbase + rc1];
    }
#pragma unroll
    for (int ni = 0; ni < 4; ni++) {
      const int rbase = (wn + ni * 16 + lr) * 64;
      b8[ni][0] = *(const bf16v8*)&Bd[rbase + rc0];
      b8[ni][1] = *(const bf16v8*)&Bd[rbase + rc1];
    }
    __builtin_amdgcn_s_setprio(1);
#pragma unroll
    for (int ks = 0; ks < 2; ks++)
#pragma unroll
      for (int mi = 0; mi < 4; mi++)
#pragma unroll
        for (int ni = 0; ni < 4; ni++)
          acc[mi][ni] = __builtin_amdgcn_mfma_f32_16x16x32_bf16(a8[mi][ks], b8[ni][ks], acc[mi][ni], 0, 0, 0);
    __builtin_amdgcn_s_setprio(0);
    asm volatile("s_waitcnt lgkmcnt(0)\n\ts_barrier" ::: "memory");
    if (kt + 2 < NT) STAGE(d, kt + 2);
  }

#pragma unroll
  for (int mi = 0; mi < 4; mi++) {
    const int r0 = m0 + wm + mi * 16 + hi * 4;
#pragma unroll
    for (int ni = 0; ni < 4; ni++) {
      const int col = n0 + wn + ni * 16 + lr;
#pragma unroll
      for (int j = 0; j < 4; j++) {
        (Cp + (long)bz * 3538944)[(long)(r0 + j) * 3072 + col] = f2bf(acc[mi][ni][j]);
      }
    }
  }
}

// ---------------------------------------------------------------------------
// norm3: fused {z=0: LN(x f32)}, {z=1: patch+LN(dr_ref)}, {z=2: patch+LN(cl_ref)}
// -> bf16 slots of xkv_ln. grid (1152, 4, 3), block 256.
// ---------------------------------------------------------------------------
__global__ __launch_bounds__(256) void norm3_kernel(const float* __restrict__ X,
    const float* __restrict__ dr_ref, const float* __restrict__ cl_ref,
    const float* __restrict__ g, const float* __restrict__ be,
    u16* __restrict__ Y3, int shift)
{
  const int n = blockIdx.x, b = blockIdx.y, z = blockIdx.z, t = threadIdx.x;
  const long row = (long)b * 1152 + n;
  u16* yr = Y3 + (size_t)z * 4718592 + row * 1024;
  const int d0 = t * 4;
  float v[4];
  if (z == 0) {
    const f32x4 vv = *(const f32x4*)&X[row * 1024 + d0];
    v[0] = vv[0]; v[1] = vv[1]; v[2] = vv[2]; v[3] = vv[3];
  } else {
    if (n >= 1089) {
      const u16x4 zz = {0, 0, 0, 0};
      *(u16x4*)&yr[d0] = zz;
      return;
    }
    const float* img = (z == 1) ? dr_ref : cl_ref;
    const int p = shift * 2;
    const int ph = n / 33, pw = n - ph * 33;
    const int c = d0 >> 6, kh = (d0 >> 3) & 7, kw0 = d0 & 7;
    const int hh = refl(ph * 8 + kh - p, 256);
    const float* src = img + ((long)(b * 16 + c) * 256 + hh) * 256;
#pragma unroll
    for (int i = 0; i < 4; i++) v[i] = src[refl(pw * 8 + kw0 + i - p, 256)];
  }
  float s = v[0] + v[1] + v[2] + v[3];
  float q = v[0]*v[0] + v[1]*v[1] + v[2]*v[2] + v[3]*v[3];
#pragma unroll
  for (int off = 32; off; off >>= 1) { s += __shfl_xor(s, off); q += __shfl_xor(q, off); }
  __shared__ float red[8];
  if ((t & 63) == 0) { red[t >> 6] = s; red[4 + (t >> 6)] = q; }
  __syncthreads();
  s = red[0] + red[1] + red[2] + red[3];
  q = red[4] + red[5] + red[6] + red[7];
  const float mean = s * (1.f / 1024.f);
  const float rstd = rsqrtf(q * (1.f / 1024.f) - mean * mean + 1e-5f);
  u16x4 o;
#pragma unroll
  for (int i = 0; i < 4; i++) o[i] = f2bf((v[i] - mean) * rstd * g[d0 + i] + be[d0 + i]);
  *(u16x4*)&yr[d0] = o;
}

// ---------------------------------------------------------------------------
// LayerNorm: f32 [row,1024] -> bf16 (FF pre-norm)
// ---------------------------------------------------------------------------
__global__ __launch_bounds__(256) void ln_kernel(const float* __restrict__ X,
    const float* __restrict__ g, const float* __restrict__ be, u16* __restrict__ Y)
{
  const long row = blockIdx.x;
  const int t = threadIdx.x;
  const float* xr = X + row * 1024;
  f32x4 v = *(const f32x4*)&xr[t * 4];
  float s = v[0] + v[1] + v[2] + v[3];
  float q = v[0]*v[0] + v[1]*v[1] + v[2]*v[2] + v[3]*v[3];
#pragma unroll
  for (int off = 32; off; off >>= 1) { s += __shfl_xor(s, off); q += __shfl_xor(q, off); }
  __shared__ float red[8];
  if ((t & 63) == 0) { red[t >> 6] = s; red[4 + (t >> 6)] = q; }
  __syncthreads();
  s = red[0] + red[1] + red[2] + red[3];
  q = red[4] + red[5] + red[6] + red[7];
  const float mean = s * (1.f / 1024.f);
  const float rstd = rsqrtf(q * (1.f / 1024.f) - mean * mean + 1e-5f);
  f32x4 gv = *(const f32x4*)&g[t * 4];
  f32x4 bv = *(const f32x4*)&be[t * 4];
  u16x4 o;
#pragma unroll
  for (int i = 0; i < 4; i++) o[i] = f2bf((v[i] - mean) * rstd * gv[i] + bv[i]);
  *(u16x4*)&Y[row * 1024 + t * 4] = o;
}

// ---------------------------------------------------------------------------
// Patch (reflect-pad + unfold) -> f32 x buffer; pad rows zeroed. rows=1152/b
// ---------------------------------------------------------------------------
__global__ __launch_bounds__(256) void patch_kernel(const float* __restrict__ img,
    float* __restrict__ X, int shift)
{
  const int n = blockIdx.x, b = blockIdx.y, t = threadIdx.x;
  float* xr = X + ((long)b * 1152 + n) * 1024;
  if (n >= 1089) {
    const f32x4 z = {0.f, 0.f, 0.f, 0.f};
    *(f32x4*)&xr[t * 4] = z;
    return;
  }
  const int p = shift * 2;
  const int ph = n / 33, pw = n - ph * 33;
  const int d0 = t * 4;
  const int c = d0 >> 6, kh = (d0 >> 3) & 7, kw0 = d0 & 7;
  const int hh = refl(ph * 8 + kh - p, 256);
  const float* src = img + ((long)(b * 16 + c) * 256 + hh) * 256;
  f32x4 v;
#pragma unroll
  for (int i = 0; i < 4; i++) v[i] = src[refl(pw * 8 + kw0 + i - p, 256)];
  *(f32x4*)&xr[d0] = v;
}

// ---------------------------------------------------------------------------
// Row softmax from bf16 logits, masked (cols < 1089), scale 1/32, bf16 out.
// ---------------------------------------------------------------------------
__global__ __launch_bounds__(256) void softmax_kernel(const u16* __restrict__ L,
    u16* __restrict__ P)
{
  const int r = blockIdx.x, b = blockIdx.y, t = threadIdx.x;
  const u16* Lr = L + ((long)b * 1152 + r) * 1152;
  u16* Pr = P + ((long)b * 1152 + r) * 1152;
  float v[5];
  float mx = -1e30f;
#pragma unroll
  for (int i = 0; i < 5; i++) {
    const int j = t + i * 256;
    v[i] = (j < 1089) ? bf2f(Lr[j]) * 0.03125f : -1e30f;
    mx = fmaxf(mx, v[i]);
  }
#pragma unroll
  for (int off = 32; off; off >>= 1) mx = fmaxf(mx, __shfl_xor(mx, off));
  __shared__ float sm[4];
  if ((t & 63) == 0) sm[t >> 6] = mx;
  __syncthreads();
  mx = fmaxf(fmaxf(sm[0], sm[1]), fmaxf(sm[2], sm[3]));
  float p[5];
  float s = 0.f;
#pragma unroll
  for (int i = 0; i < 5; i++) {
    const int j = t + i * 256;
    p[i] = (j < 1089) ? __expf(v[i] - mx) : 0.f;
    s += p[i];
  }
#pragma unroll
  for (int off = 32; off; off >>= 1) s += __shfl_xor(s, off);
  __shared__ float ss[4];
  if ((t & 63) == 0) ss[t >> 6] = s;
  __syncthreads();
  const float inv = 1.f / (ss[0] + ss[1] + ss[2] + ss[3]);
#pragma unroll
  for (int i = 0; i < 5; i++) {
    const int j = t + i * 256;
    if (j < 1152) Pr[j] = f2bf(p[i] * inv);
  }
}

// ---------------------------------------------------------------------------
// Weight transpose (f32 -> bf16, W[K][N] -> Wt[N][K])
// ---------------------------------------------------------------------------
__global__ __launch_bounds__(256) void wtrans_kernel(const float* __restrict__ W,
    u16* __restrict__ Wt, int K, int N)
{
  __shared__ float tile[32][33];
  const int n0 = blockIdx.x * 32, k0 = blockIdx.y * 32;
  const int tx = threadIdx.x & 31, ty = threadIdx.x >> 5;
#pragma unroll
  for (int i = 0; i < 4; i++)
    tile[ty + 8 * i][tx] = W[(long)(k0 + ty + 8 * i) * N + n0 + tx];
  __syncthreads();
#pragma unroll
  for (int i = 0; i < 4; i++)
    Wt[(long)(n0 + ty + 8 * i) * K + k0 + tx] = f2bf(tile[tx][ty + 8 * i]);
}

__global__ __launch_bounds__(256) void catbias_kernel(const float* __restrict__ a,
    const float* __restrict__ b, const float* __restrict__ c, float* __restrict__ o)
{
  const int i = blockIdx.x * 256 + threadIdx.x;  // 3072
  o[i] = a[i]; o[3072 + i] = b[i]; o[6144 + i] = c[i];
}

// ---------------------------------------------------------------------------
// Unpatch (inverse unfold + crop) -> f32 output
// ---------------------------------------------------------------------------
__global__ __launch_bounds__(256) void unpatch_kernel(const float* __restrict__ X,
    float* __restrict__ out)
{
  const int idx = blockIdx.x * 256 + threadIdx.x;  // one per 4 floats
  const int w = (idx & 63) * 4;
  const int h = (idx >> 6) & 255;
  const int c = (idx >> 14) & 15;
  const int b = idx >> 18;
  const int ph = h >> 3, kh = h & 7, pw = w >> 3, kw = w & 7;
  const long row = (long)b * 1152 + ph * 33 + pw;
  const int d = c * 64 + kh * 8 + kw;
  const f32x4 v = *(const f32x4*)&X[row * 1024 + d];
  *(f32x4*)&out[((long)(b * 16 + c) * 256 + h) * 256 + w] = v;
}

// ---------------------------------------------------------------------------
extern "C" void kernel_launch(void* const* d_in, const int* in_sizes, int n_in,
                              void* d_out, int out_size, void* d_ws, size_t ws_size,
                              hipStream_t stream)
{
  (void)in_sizes; (void)n_in; (void)out_size; (void)ws_size;
  const float* dr_img = (const float*)d_in[0];
  const float* dr_ref = (const float*)d_in[1];
  const float* cl_ref = (const float*)d_in[2];
  const float* ln_g = (const float*)d_in[3];
  const float* ln_be = (const float*)d_in[4];
  const float* Wq = (const float*)d_in[5];
  const float* bq = (const float*)d_in[6];
  const float* Wk = (const float*)d_in[7];
  const float* bk = (const float*)d_in[8];
  const float* Wv = (const float*)d_in[9];
  const float* bv = (const float*)d_in[10];
  const float* Wo = (const float*)d_in[11];
  const float* bo = (const float*)d_in[12];
  const float* ffg = (const float*)d_in[13];
  const float* ffb = (const float*)d_in[14];
  const float* W1 = (const float*)d_in[15];
  const float* b1 = (const float*)d_in[16];
  const float* W2 = (const float*)d_in[17];
  const float* b2 = (const float*)d_in[18];

  const long R = 1152;                 // padded tokens per batch (9*128)
  const long MR = 4 * R;               // 4608 = 18*256

  char* ws = (char*)d_ws;
  size_t off = 0;
  auto alloc = [&](size_t bytes) -> void* {
    void* pp = ws + off;
    off += (bytes + 255) & ~(size_t)255;
    return pp;
  };
  float* x    = (float*)alloc((size_t)MR * 1024 * 4);
  u16* xkv_ln = (u16*)alloc((size_t)3 * MR * 1024 * 2);  // x_ln / k_ln(=FF h) / v_ln
  u16* qkv    = (u16*)alloc((size_t)3 * MR * 3072 * 2);  // q(=attn_out) / k / V^T[3072][4608]
  u16* lgt    = (u16*)alloc((size_t)4 * R * R * 2);      // bf16 logits
  u16* P      = (u16*)alloc((size_t)4 * R * R * 2);
  u16* Wqkv_t = (u16*)alloc((size_t)3 * 3072 * 1024 * 2);
  u16* Wo_t   = (u16*)alloc((size_t)1024 * 3072 * 2);
  u16* W1_t   = (u16*)alloc((size_t)1024 * 1024 * 2);
  u16* W2_t   = (u16*)alloc((size_t)1024 * 1024 * 2);
  float* bcat = (float*)alloc((size_t)3 * 3072 * 4);

  u16* x_ln = xkv_ln;
  u16* v_ln = xkv_ln + (size_t)2 * MR * 1024;
  u16* h    = xkv_ln + (size_t)MR * 1024;      // FF hidden aliases k_ln slot
  u16* qp   = qkv;
  u16* kp   = qkv + (size_t)MR * 3072;
  u16* vT   = qkv + (size_t)2 * MR * 3072;     // [3072][4608]
  u16* Wv_t = Wqkv_t + (size_t)2 * 3072 * 1024;

  wtrans_kernel<<<dim3(96, 32), 256, 0, stream>>>(Wq, Wqkv_t, 1024, 3072);
  wtrans_kernel<<<dim3(96, 32), 256, 0, stream>>>(Wk, Wqkv_t + (size_t)3072 * 1024, 1024, 3072);
  wtrans_kernel<<<dim3(96, 32), 256, 0, stream>>>(Wv, Wv_t, 1024, 3072);
  wtrans_kernel<<<dim3(32, 96), 256, 0, stream>>>(Wo, Wo_t, 3072, 1024);
  wtrans_kernel<<<dim3(32, 32), 256, 0, stream>>>(W1, W1_t, 1024, 1024);
  wtrans_kernel<<<dim3(32, 32), 256, 0, stream>>>(W2, W2_t, 1024, 1024);
  catbias_kernel<<<12, 256, 0, stream>>>(bq, bk, bv, bcat);

  patch_kernel<<<dim3(1152, 4), 256, 0, stream>>>(dr_img, x, 0);

  const long sAp = (long)MR * 1024;        // proj A slot stride
  const long sBp = (long)3072 * 1024;      // proj W slot stride
  const long sCp = (long)MR * 3072;        // proj C slot stride
  const long sQb = R * 3072;               // per-batch stride in qp/kp
  const long sLb = R * R;

  for (int shift = 0; shift < 4; shift++) {
    // fused: LN(x) -> slot0 | patch+LN(dr_ref) -> slot1 | patch+LN(cl_ref) -> slot2
    norm3_kernel<<<dim3(1152, 4, 3), 256, 0, stream>>>(
        x, dr_ref, cl_ref, ln_g, ln_be, xkv_ln, shift);

    // Q/K projections, z-batched: [4608,1024] x [3072,1024]^T -> [4608,3072]
    gemm256<EPI_BF16_BIAS><<<dim3(12, 18, 2), 512, 131072, stream>>>(
        xkv_ln, Wqkv_t, qkv, bcat, 1024, 3072, sAp, sBp, sCp, 3072);

    // V^T projection (operand swap): [3072,1024] x [4608,1024]^T -> V^T[3072][4608]
    gemm256<EPI_BF16_BIASROW><<<dim3(18, 12, 1), 512, 131072, stream>>>(
        Wv_t, v_ln, vT, bv, 1024, (int)MR, 0, 0, 0, 0);

    // logits: per batch [1152,3072] x [1152,3072]^T -> [1152,1152] bf16
    gemm128<EPI_BF16><<<dim3(9, 9, 4), 512, 65536, stream>>>(
        qp, kp, lgt, nullptr, 3072, 3072, 1152, sQb, sQb, sLb);

    softmax_kernel<<<dim3(1152, 4), 256, 0, stream>>>(lgt, P);

    // PV: per batch [1152,1152] x V^T -> [1152,3072] (128x256 tile, 64x64 waves)
    gemm_pv<<<dim3(12, 9, 4), 512, 98304, stream>>>(P, vT, qp);

    // out-proj + residual: [4608,3072] x [1024,3072]^T -> += x
    gemm128<EPI_F32_RES><<<dim3(8, 36, 1), 512, 65536, stream>>>(
        qp, Wo_t, x, bo, 3072, 3072, 1024, 0, 0, 0);

    ln_kernel<<<(int)MR, 256, 0, stream>>>(x, ffg, ffb, x_ln);
    gemm128<EPI_GELU><<<dim3(8, 36, 1), 512, 65536, stream>>>(
        x_ln, W1_t, h, b1, 1024, 1024, 1024, 0, 0, 0);
    gemm128<EPI_F32_RES><<<dim3(8, 36, 1), 512, 65536, stream>>>(
        h, W2_t, x, b2, 1024, 1024, 1024, 0, 0, 0);
  }

  unpatch_kernel<<<4096, 256, 0, stream>>>(x, (float*)d_out);
}